// Round 6
// baseline (142.397 us; speedup 1.0000x reference)
//
#include <hip/hip_runtime.h>
#include <stdint.h>

// Chamfer distance, B=4, N=M=8192, fp32 [B][N][3], out[B] = d01+d10.
//
// R6: DIAGNOSTIC round, minimal delta from passing R4.
// R5's failure isolated to the inline-asm v_max3_f32 reading MFMA D-regs
// (hazard-recognizer gap around INLINEASM + MFMA -> reads partially-written
// tiles). Reverted to R4's fmaxf merge (clang fuses to v_max3 anyway),
// launch_bounds(256,4), no asm in the data path.
// Kept: REPEAT=8 (idempotent max-merge re-runs the pass loop) so the sweep
// finally exceeds the ~40us harness poison-fills and shows its counters;
// s_setprio(1) around the MFMA cluster (runtime hint, correctness-neutral).
// R7 strips REPEAT and acts on the counters.

typedef __bf16 bf16x8 __attribute__((ext_vector_type(8)));
typedef float  f32x16 __attribute__((ext_vector_type(16)));
typedef float  f32x4  __attribute__((ext_vector_type(4)));

constexpr int B     = 4;
constexpr int NPTS  = 8192;
constexpr int BLOCK = 256;
constexpr int QPB   = 256;             // 4 waves * 64 queries
constexpr int QBLKS = NPTS / QPB;      // 32
constexpr int CH    = 4;               // point chunks per (b,dir)
constexpr int CPTS  = NPTS / CH;       // 2048 points per chunk
constexpr int SPTS  = 512;             // points per LDS pass (16 KB/buffer)
constexpr int NPASS = CPTS / SPTS;     // 4
constexpr int TPP   = SPTS / 32;       // 16 tiles per pass
constexpr int GRPS  = NPTS / 32;       // 256 point-groups per cloud
constexpr int PASSBYTES = SPTS * 32;   // 16384 B
constexpr int RSTRIDE = 36;            // padded f32 per reduce row
constexpr int SMEMB = BLOCK * RSTRIDE * 4;            // 36864 B
constexpr int REPEAT = 8;              // DIAGNOSTIC ONLY (max is idempotent)
constexpr size_t CMBYTES = (size_t)2 * B * CH * NPTS * sizeof(float); // 1 MB

__device__ inline void gload_lds16(const void* g, void* l) {
    __builtin_amdgcn_global_load_lds(
        (const __attribute__((address_space(1))) uint32_t*)g,
        (__attribute__((address_space(3))) uint32_t*)l, 16, 0, 0);
}

// ---- Kernel 1: prep point fragments (g-major per 32-pt group); zero out ---
// group base (1024 B): frags g0 of pts 0..31, then frags g1 of pts 0..31.
// g0(k0-7) = [pxh,pyh,pzh, pxl,pyl,pzl, pxh,pyh]
// g1(k8-15)= [pzh, nh, nl, pxl,pyl,pzl, 0, 0]
__global__ __launch_bounds__(BLOCK) void chamfer_prep(
    const float* __restrict__ tpl, const float* __restrict__ src,
    bf16x8* __restrict__ efrag, float* __restrict__ out)
{
    const int pt  = blockIdx.x * BLOCK + threadIdx.x;
    const int c   = blockIdx.y;              // dir*B + b
    const int b   = c & (B - 1);
    const int dir = c >> 2;
    const float* db = (dir == 0 ? src : tpl) + (size_t)b * NPTS * 3;

    if (blockIdx.x == 0 && c == 0 && threadIdx.x < B) out[threadIdx.x] = 0.f;

    float x = db[3 * pt], y = db[3 * pt + 1], z = db[3 * pt + 2];
    float n = -0.5f * (x * x + y * y + z * z);
    __bf16 hx = (__bf16)x, hy = (__bf16)y, hz = (__bf16)z;
    __bf16 lx = (__bf16)(x - (float)hx);
    __bf16 ly = (__bf16)(y - (float)hy);
    __bf16 lz = (__bf16)(z - (float)hz);
    __bf16 nh = (__bf16)n;
    __bf16 nl = (__bf16)(n - (float)nh);
    const __bf16 zb = (__bf16)0.0f;

    const int gi = pt >> 5, sl = pt & 31;
    size_t gb = ((size_t)c * GRPS + gi) * 64;
    efrag[gb + sl]      = (bf16x8){hx, hy, hz, lx, ly, lz, hx, hy};
    efrag[gb + 32 + sl] = (bf16x8){hz, nh, nl, lx, ly, lz, zb, zb};
}

// ---- Kernel 2: MFMA sweep -------------------------------------------------
__global__ __launch_bounds__(BLOCK, 4) void chamfer_sweep(
    const float* __restrict__ tpl, const float* __restrict__ src,
    const bf16x8* __restrict__ efrag,
    float* __restrict__ cm)                  // [2*B][CH][NPTS] chunk maxima
{
    __shared__ char smem[SMEMB];             // sbuf (2x16KB) / reduce (36.9KB)

    const int tid = threadIdx.x;
    const int l   = tid & 63;
    const int w   = tid >> 6;
    const int h   = l >> 5;                  // k-group (0: k0-7, 1: k8-15)
    const int r32 = l & 31;                  // A row / B col within tile
    const int c   = blockIdx.z;              // dir*B + b
    const int b   = c & (B - 1);
    const int dir = c >> 2;
    const float* q = (dir == 0 ? tpl : src) + (size_t)b * NPTS * 3;
    const int qbase = blockIdx.x * QPB + w * 64;
    const char* eb  = (const char*)efrag
                    + ((size_t)c * GRPS + blockIdx.y * (CPTS / 32)) * 1024;

    // Prologue: issue pass-0 staging first (latency hides under fa build).
    #pragma unroll
    for (int i = 0; i < 4; ++i) {
        int off = (w * 4 + i) * 1024;
        gload_lds16(eb + off + l * 16, smem + off);
    }

    // A fragments: row = r32, k = h*8 + e. 64 queries per wave.
    // g0 = [qxh,qyh,qzh, qxh,qyh,qzh, qxl,qyl]; g1 = [qzl,1,1, qxl,qyl,qzl,0,0]
    const __bf16 one = (__bf16)1.0f, zb = (__bf16)0.0f;
    bf16x8 fa[2];
    #pragma unroll
    for (int f = 0; f < 2; ++f) {
        int qi = qbase + f * 32 + r32;
        float x = q[3 * qi], y = q[3 * qi + 1], z = q[3 * qi + 2];
        __bf16 hx = (__bf16)x, hy = (__bf16)y, hz = (__bf16)z;
        __bf16 lx = (__bf16)(x - (float)hx);
        __bf16 ly = (__bf16)(y - (float)hy);
        __bf16 lz = (__bf16)(z - (float)hz);
        if (h == 0) fa[f] = (bf16x8){hx, hy, hz, hx, hy, hz, lx, ly};
        else        fa[f] = (bf16x8){lz, one, one, lx, ly, lz, zb, zb};
    }

    f32x16 best0, best1, zc;
    #pragma unroll
    for (int r = 0; r < 16; ++r) { best0[r] = -3.4e38f; best1[r] = -3.4e38f; zc[r] = 0.0f; }

    const int idx0 = h * 32 + r32;           // contiguous 16B/lane per half-wave
    const int NGP  = REPEAT * NPASS;         // global pass count (diagnostic x8)
    for (int gp = 0; gp < NGP; ++gp) {
        __syncthreads();                     // this pass's loads landed; other buffer free
        if (gp + 1 < NGP) {
            const char* ebn = eb + ((gp + 1) & (NPASS - 1)) * PASSBYTES;
            char* dst = smem + ((gp + 1) & 1) * 16384;
            #pragma unroll
            for (int i = 0; i < 4; ++i) {
                int off = (w * 4 + i) * 1024;
                gload_lds16(ebn + off + l * 16, dst + off);
            }
        }
        const bf16x8* sb = (const bf16x8*)(smem + (gp & 1) * 16384);
        __builtin_amdgcn_s_setprio(1);
        #pragma unroll
        for (int t = 0; t < TPP; t += 2) {
            bf16x8 bv0 = sb[t * 64 + idx0];
            bf16x8 bv1 = sb[(t + 1) * 64 + idx0];
            f32x16 d0 = __builtin_amdgcn_mfma_f32_32x32x16_bf16(fa[0], bv0, zc, 0, 0, 0);
            f32x16 d1 = __builtin_amdgcn_mfma_f32_32x32x16_bf16(fa[0], bv1, zc, 0, 0, 0);
            #pragma unroll
            for (int r = 0; r < 16; ++r)
                best0[r] = fmaxf(fmaxf(best0[r], d0[r]), d1[r]);   // -> v_max3
            __builtin_amdgcn_sched_barrier(0);   // cap live D-tiles (VGPR fit)
            d0 = __builtin_amdgcn_mfma_f32_32x32x16_bf16(fa[1], bv0, zc, 0, 0, 0);
            d1 = __builtin_amdgcn_mfma_f32_32x32x16_bf16(fa[1], bv1, zc, 0, 0, 0);
            #pragma unroll
            for (int r = 0; r < 16; ++r)
                best1[r] = fmaxf(fmaxf(best1[r], d1[r]), d0[r]);
            __builtin_amdgcn_sched_barrier(0);
        }
        __builtin_amdgcn_s_setprio(0);
    }

    // Epilogue: LDS transpose reduce (no wave shuffles, no atomics).
    // D layout: col = r32, row = (r&3) + 8*(r>>2) + 4*h.
    __syncthreads();                         // all waves done reading sbuf
    float* red = (float*)smem;
    #pragma unroll
    for (int r = 0; r < 16; ++r) {
        int row = (r & 3) + 8 * (r >> 2) + 4 * h;
        red[(w * 64 + row) * RSTRIDE + r32]      = best0[r];
        red[(w * 64 + 32 + row) * RSTRIDE + r32] = best1[r];
    }
    __syncthreads();
    const float* rr = red + tid * RSTRIDE;   // 144B stride: 2-way only (free)
    float m = -3.4e38f;
    #pragma unroll
    for (int j = 0; j < 8; ++j) {
        f32x4 v = *(const f32x4*)(rr + 4 * j);
        m = fmaxf(m, fmaxf(fmaxf(v.x, v.y), fmaxf(v.z, v.w)));
    }
    cm[((size_t)c * CH + blockIdx.y) * NPTS + blockIdx.x * QPB + tid] = m;
}

// ---- Kernel 3: dist = |q|^2 - 2*max_chunks(maxd'), mean, out[b] += --------
__global__ __launch_bounds__(256) void chamfer_final(
    const float* __restrict__ tpl, const float* __restrict__ src,
    const float* __restrict__ cm, float* __restrict__ out)
{
    __shared__ float red[256];
    const int z = blockIdx.x;                // dir*B + b
    const float* qc = (z < B ? tpl : src) + (size_t)(z & (B - 1)) * NPTS * 3;
    const float* cz = cm + (size_t)z * CH * NPTS;

    float s = 0.f;
    for (int i = threadIdx.x; i < NPTS; i += 256) {
        float md = fmaxf(fmaxf(cz[i], cz[NPTS + i]),
                         fmaxf(cz[2 * NPTS + i], cz[3 * NPTS + i]));
        float x = qc[3 * i], y = qc[3 * i + 1], zz = qc[3 * i + 2];
        s += fmaf(md, -2.0f, x * x + y * y + zz * zz);
    }
    red[threadIdx.x] = s;
    __syncthreads();
    #pragma unroll
    for (int off = 128; off > 0; off >>= 1) {
        if (threadIdx.x < off) red[threadIdx.x] += red[threadIdx.x + off];
        __syncthreads();
    }
    if (threadIdx.x == 0)
        atomicAdd(&out[z & (B - 1)], red[0] * (1.0f / NPTS));  // 2 addends/b
}

extern "C" void kernel_launch(void* const* d_in, const int* in_sizes, int n_in,
                              void* d_out, int out_size, void* d_ws, size_t ws_size,
                              hipStream_t stream) {
    const float* tpl = (const float*)d_in[0];
    const float* src = (const float*)d_in[1];
    float* out = (float*)d_out;
    float* cm      = (float*)d_ws;                             // 1 MB
    bf16x8* efrag  = (bf16x8*)((char*)d_ws + CMBYTES);         // 2 MB

    chamfer_prep <<<dim3(NPTS / BLOCK, 2 * B), BLOCK, 0, stream>>>(tpl, src, efrag, out);
    chamfer_sweep<<<dim3(QBLKS, CH, 2 * B),    BLOCK, 0, stream>>>(tpl, src, efrag, cm);
    chamfer_final<<<2 * B, 256, 0, stream>>>(tpl, src, cm, out);
}

// Round 7
// 38.671 us; speedup vs baseline: 3.6823x; 3.6823x over previous
//
#include <hip/hip_runtime.h>
#include <stdint.h>

// Chamfer distance, B=4, N=M=8192, fp32 [B][N][3], out[B] = d01+d10.
//
// R7: strip R6's diagnostic REPEAT=8 (sweep measured: 16.2us/unit, MfmaUtil
// 49%, VALUBusy 58%, conflicts 0, VGPR 52). Keep the setprio(1) MFMA cluster
// (R4->R6 per-pass delta ~ -40%, T5 on this 4-blocks/CU structure).
// VALU bloat (~22 instr/mfma vs 8-max3 floor) + VGPR=52 points at AGPR
// D-tiles + copies and/or sched_barrier-forced serialization:
//  - drop both sched_barrier(0)s (let merge(t) pipeline under mfma(t+1));
//  - launch_bounds(256,3): 168-VGPR budget so ~100 live f32 stay in arch
//    VGPRs (occupancy stays LDS-capped at 4 blocks/CU).
// Numerics identical to the R4/R6 verified path.

typedef __bf16 bf16x8 __attribute__((ext_vector_type(8)));
typedef float  f32x16 __attribute__((ext_vector_type(16)));
typedef float  f32x4  __attribute__((ext_vector_type(4)));

constexpr int B     = 4;
constexpr int NPTS  = 8192;
constexpr int BLOCK = 256;
constexpr int QPB   = 256;             // 4 waves * 64 queries
constexpr int QBLKS = NPTS / QPB;      // 32
constexpr int CH    = 4;               // point chunks per (b,dir)
constexpr int CPTS  = NPTS / CH;       // 2048 points per chunk
constexpr int SPTS  = 512;             // points per LDS pass (16 KB/buffer)
constexpr int NPASS = CPTS / SPTS;     // 4
constexpr int TPP   = SPTS / 32;       // 16 tiles per pass
constexpr int GRPS  = NPTS / 32;       // 256 point-groups per cloud
constexpr int PASSBYTES = SPTS * 32;   // 16384 B
constexpr int RSTRIDE = 36;            // padded f32 per reduce row
constexpr int SMEMB = BLOCK * RSTRIDE * 4;            // 36864 B
constexpr size_t CMBYTES = (size_t)2 * B * CH * NPTS * sizeof(float); // 1 MB

__device__ inline void gload_lds16(const void* g, void* l) {
    __builtin_amdgcn_global_load_lds(
        (const __attribute__((address_space(1))) uint32_t*)g,
        (__attribute__((address_space(3))) uint32_t*)l, 16, 0, 0);
}

// ---- Kernel 1: prep point fragments (g-major per 32-pt group); zero out ---
// group base (1024 B): frags g0 of pts 0..31, then frags g1 of pts 0..31.
// g0(k0-7) = [pxh,pyh,pzh, pxl,pyl,pzl, pxh,pyh]
// g1(k8-15)= [pzh, nh, nl, pxl,pyl,pzl, 0, 0]
__global__ __launch_bounds__(BLOCK) void chamfer_prep(
    const float* __restrict__ tpl, const float* __restrict__ src,
    bf16x8* __restrict__ efrag, float* __restrict__ out)
{
    const int pt  = blockIdx.x * BLOCK + threadIdx.x;
    const int c   = blockIdx.y;              // dir*B + b
    const int b   = c & (B - 1);
    const int dir = c >> 2;
    const float* db = (dir == 0 ? src : tpl) + (size_t)b * NPTS * 3;

    if (blockIdx.x == 0 && c == 0 && threadIdx.x < B) out[threadIdx.x] = 0.f;

    float x = db[3 * pt], y = db[3 * pt + 1], z = db[3 * pt + 2];
    float n = -0.5f * (x * x + y * y + z * z);
    __bf16 hx = (__bf16)x, hy = (__bf16)y, hz = (__bf16)z;
    __bf16 lx = (__bf16)(x - (float)hx);
    __bf16 ly = (__bf16)(y - (float)hy);
    __bf16 lz = (__bf16)(z - (float)hz);
    __bf16 nh = (__bf16)n;
    __bf16 nl = (__bf16)(n - (float)nh);
    const __bf16 zb = (__bf16)0.0f;

    const int gi = pt >> 5, sl = pt & 31;
    size_t gb = ((size_t)c * GRPS + gi) * 64;
    efrag[gb + sl]      = (bf16x8){hx, hy, hz, lx, ly, lz, hx, hy};
    efrag[gb + 32 + sl] = (bf16x8){hz, nh, nl, lx, ly, lz, zb, zb};
}

// ---- Kernel 2: MFMA sweep -------------------------------------------------
__global__ __launch_bounds__(BLOCK, 3) void chamfer_sweep(
    const float* __restrict__ tpl, const float* __restrict__ src,
    const bf16x8* __restrict__ efrag,
    float* __restrict__ cm)                  // [2*B][CH][NPTS] chunk maxima
{
    __shared__ char smem[SMEMB];             // sbuf (2x16KB) / reduce (36.9KB)

    const int tid = threadIdx.x;
    const int l   = tid & 63;
    const int w   = tid >> 6;
    const int h   = l >> 5;                  // k-group (0: k0-7, 1: k8-15)
    const int r32 = l & 31;                  // A row / B col within tile
    const int c   = blockIdx.z;              // dir*B + b
    const int b   = c & (B - 1);
    const int dir = c >> 2;
    const float* q = (dir == 0 ? tpl : src) + (size_t)b * NPTS * 3;
    const int qbase = blockIdx.x * QPB + w * 64;
    const char* eb  = (const char*)efrag
                    + ((size_t)c * GRPS + blockIdx.y * (CPTS / 32)) * 1024;

    // Prologue: issue pass-0 staging first (latency hides under fa build).
    #pragma unroll
    for (int i = 0; i < 4; ++i) {
        int off = (w * 4 + i) * 1024;
        gload_lds16(eb + off + l * 16, smem + off);
    }

    // A fragments: row = r32, k = h*8 + e. 64 queries per wave.
    // g0 = [qxh,qyh,qzh, qxh,qyh,qzh, qxl,qyl]; g1 = [qzl,1,1, qxl,qyl,qzl,0,0]
    const __bf16 one = (__bf16)1.0f, zb = (__bf16)0.0f;
    bf16x8 fa[2];
    #pragma unroll
    for (int f = 0; f < 2; ++f) {
        int qi = qbase + f * 32 + r32;
        float x = q[3 * qi], y = q[3 * qi + 1], z = q[3 * qi + 2];
        __bf16 hx = (__bf16)x, hy = (__bf16)y, hz = (__bf16)z;
        __bf16 lx = (__bf16)(x - (float)hx);
        __bf16 ly = (__bf16)(y - (float)hy);
        __bf16 lz = (__bf16)(z - (float)hz);
        if (h == 0) fa[f] = (bf16x8){hx, hy, hz, hx, hy, hz, lx, ly};
        else        fa[f] = (bf16x8){lz, one, one, lx, ly, lz, zb, zb};
    }

    f32x16 best0, best1, zc;
    #pragma unroll
    for (int r = 0; r < 16; ++r) { best0[r] = -3.4e38f; best1[r] = -3.4e38f; zc[r] = 0.0f; }

    const int idx0 = h * 32 + r32;           // contiguous 16B/lane per half-wave
    for (int gp = 0; gp < NPASS; ++gp) {
        __syncthreads();                     // this pass's loads landed; other buffer free
        if (gp + 1 < NPASS) {
            const char* ebn = eb + (gp + 1) * PASSBYTES;
            char* dst = smem + ((gp + 1) & 1) * 16384;
            #pragma unroll
            for (int i = 0; i < 4; ++i) {
                int off = (w * 4 + i) * 1024;
                gload_lds16(ebn + off + l * 16, dst + off);
            }
        }
        const bf16x8* sb = (const bf16x8*)(smem + (gp & 1) * 16384);
        __builtin_amdgcn_s_setprio(1);
        #pragma unroll
        for (int t = 0; t < TPP; t += 2) {
            bf16x8 bv0 = sb[t * 64 + idx0];
            bf16x8 bv1 = sb[(t + 1) * 64 + idx0];
            f32x16 d0 = __builtin_amdgcn_mfma_f32_32x32x16_bf16(fa[0], bv0, zc, 0, 0, 0);
            f32x16 d1 = __builtin_amdgcn_mfma_f32_32x32x16_bf16(fa[0], bv1, zc, 0, 0, 0);
            f32x16 e0 = __builtin_amdgcn_mfma_f32_32x32x16_bf16(fa[1], bv0, zc, 0, 0, 0);
            f32x16 e1 = __builtin_amdgcn_mfma_f32_32x32x16_bf16(fa[1], bv1, zc, 0, 0, 0);
            #pragma unroll
            for (int r = 0; r < 16; ++r)
                best0[r] = fmaxf(fmaxf(best0[r], d0[r]), d1[r]);   // -> v_max3
            #pragma unroll
            for (int r = 0; r < 16; ++r)
                best1[r] = fmaxf(fmaxf(best1[r], e0[r]), e1[r]);
        }
        __builtin_amdgcn_s_setprio(0);
    }

    // Epilogue: LDS transpose reduce (no wave shuffles, no atomics).
    // D layout: col = r32, row = (r&3) + 8*(r>>2) + 4*h.
    __syncthreads();                         // all waves done reading sbuf
    float* red = (float*)smem;
    #pragma unroll
    for (int r = 0; r < 16; ++r) {
        int row = (r & 3) + 8 * (r >> 2) + 4 * h;
        red[(w * 64 + row) * RSTRIDE + r32]      = best0[r];
        red[(w * 64 + 32 + row) * RSTRIDE + r32] = best1[r];
    }
    __syncthreads();
    const float* rr = red + tid * RSTRIDE;   // 144B stride: 2-way only (free)
    float m = -3.4e38f;
    #pragma unroll
    for (int j = 0; j < 8; ++j) {
        f32x4 v = *(const f32x4*)(rr + 4 * j);
        m = fmaxf(m, fmaxf(fmaxf(v.x, v.y), fmaxf(v.z, v.w)));
    }
    cm[((size_t)c * CH + blockIdx.y) * NPTS + blockIdx.x * QPB + tid] = m;
}

// ---- Kernel 3: dist = |q|^2 - 2*max_chunks(maxd'), mean, out[b] += --------
__global__ __launch_bounds__(256) void chamfer_final(
    const float* __restrict__ tpl, const float* __restrict__ src,
    const float* __restrict__ cm, float* __restrict__ out)
{
    __shared__ float red[256];
    const int z = blockIdx.x;                // dir*B + b
    const float* qc = (z < B ? tpl : src) + (size_t)(z & (B - 1)) * NPTS * 3;
    const float* cz = cm + (size_t)z * CH * NPTS;

    float s = 0.f;
    for (int i = threadIdx.x; i < NPTS; i += 256) {
        float md = fmaxf(fmaxf(cz[i], cz[NPTS + i]),
                         fmaxf(cz[2 * NPTS + i], cz[3 * NPTS + i]));
        float x = qc[3 * i], y = qc[3 * i + 1], zz = qc[3 * i + 2];
        s += fmaf(md, -2.0f, x * x + y * y + zz * zz);
    }
    red[threadIdx.x] = s;
    __syncthreads();
    #pragma unroll
    for (int off = 128; off > 0; off >>= 1) {
        if (threadIdx.x < off) red[threadIdx.x] += red[threadIdx.x + off];
        __syncthreads();
    }
    if (threadIdx.x == 0)
        atomicAdd(&out[z & (B - 1)], red[0] * (1.0f / NPTS));  // 2 addends/b
}

extern "C" void kernel_launch(void* const* d_in, const int* in_sizes, int n_in,
                              void* d_out, int out_size, void* d_ws, size_t ws_size,
                              hipStream_t stream) {
    const float* tpl = (const float*)d_in[0];
    const float* src = (const float*)d_in[1];
    float* out = (float*)d_out;
    float* cm      = (float*)d_ws;                             // 1 MB
    bf16x8* efrag  = (bf16x8*)((char*)d_ws + CMBYTES);         // 2 MB

    chamfer_prep <<<dim3(NPTS / BLOCK, 2 * B), BLOCK, 0, stream>>>(tpl, src, efrag, out);
    chamfer_sweep<<<dim3(QBLKS, CH, 2 * B),    BLOCK, 0, stream>>>(tpl, src, efrag, cm);
    chamfer_final<<<2 * B, 256, 0, stream>>>(tpl, src, cm, out);
}